// Round 6
// baseline (503.826 us; speedup 1.0000x reference)
//
#include <hip/hip_runtime.h>
#include <math.h>

#define Bq 2
#define Lq 2048
#define Eq 1024
#define Hq 16
#define Dq 64

typedef __attribute__((ext_vector_type(8))) short bf16x8;
typedef __attribute__((ext_vector_type(4))) short bf16x4;
typedef __attribute__((ext_vector_type(4))) float f32x4;

__device__ __forceinline__ short f2bf(float f) {
    union { float f; unsigned u; } x; x.f = f;
    unsigned r = x.u + 0x7FFFu + ((x.u >> 16) & 1u);
    return (short)(r >> 16);
}
__device__ __forceinline__ float bf2f(short s) {
    union { unsigned u; float f; } x;
    x.u = ((unsigned)(unsigned short)s) << 16;
    return x.f;
}

// Cast Q,K,V (4096x1024 f32) and Wq,Wk,Wv (1024x1024 f32) to bf16, laid out
// consecutively in `out`: [Xq | Xk | Xv | Wqb | Wkb | Wvb].
__global__ __launch_bounds__(256) void cast_all(const float* __restrict__ Q,
                                                const float* __restrict__ K,
                                                const float* __restrict__ V,
                                                const float* __restrict__ Wq,
                                                const float* __restrict__ Wk,
                                                const float* __restrict__ Wv,
                                                short* __restrict__ out) {
    const size_t NX = (size_t)4096 * 1024 / 4;  // float4 count per X
    const size_t NW = (size_t)1024 * 1024 / 4;  // float4 count per W
    size_t id = (size_t)blockIdx.x * 256 + threadIdx.x;
    const float* src; size_t off;
    if (id < NX)              { src = Q;  off = id; }
    else if (id < 2 * NX)     { src = K;  off = id - NX; }
    else if (id < 3 * NX)     { src = V;  off = id - 2 * NX; }
    else if (id < 3 * NX + NW)     { src = Wq; off = id - 3 * NX; }
    else if (id < 3 * NX + 2 * NW) { src = Wk; off = id - 3 * NX - NW; }
    else                           { src = Wv; off = id - 3 * NX - 2 * NW; }
    float4 v = ((const float4*)src)[off];
    bf16x4 s;
    s[0] = f2bf(v.x); s[1] = f2bf(v.y); s[2] = f2bf(v.z); s[3] = f2bf(v.w);
    ((bf16x4*)out)[id] = s;
}

// All three projections in one kernel. blockIdx.y = pidx*8 + ntile.
// out[tok,feat] = sum_e Xb[tok,e]*Wb[feat,e]; bf16 in, fp32 accum, bf16 out.
// pidx 0/1 -> (B,H,L,D) + sumsq into q2/k2 ; pidx 2 -> (B,H,D,L), no sumsq.
// Block tile 64(M)x128(N), wave tile 32x64; register double-buffered K loop.
__global__ __launch_bounds__(256) void proj3_kernel(const short* __restrict__ castb,
                                                    short* __restrict__ qb,
                                                    short* __restrict__ kb,
                                                    short* __restrict__ vT,
                                                    float* __restrict__ q2,
                                                    float* __restrict__ k2) {
    const int wave = threadIdx.x >> 6;
    const int lane = threadIdx.x & 63;
    const int l15 = lane & 15, quad = lane >> 4;
    const int pidx = blockIdx.y >> 3;
    const short* Xb = castb + (size_t)pidx * 4096 * 1024;
    const short* Wb = castb + (size_t)3 * 4096 * 1024 + (size_t)pidx * 1024 * 1024;
    short* outb = (pidx == 0) ? qb : (pidx == 1) ? kb : vT;
    float* x2 = (pidx == 0) ? q2 : (pidx == 1) ? k2 : nullptr;
    const int transposed = (pidx == 2);
    const int m0 = blockIdx.x * 64 + (wave & 1) * 32;
    const int n0 = (blockIdx.y & 7) * 128 + (wave >> 1) * 64;

    const short* pa = Xb + (size_t)(m0 + l15) * Eq + quad * 8;
    const short* pw = Wb + (size_t)(n0 + l15) * Eq + quad * 8;

    f32x4 acc[2][4] = {};
    bf16x8 afc[2], bfc[4];
    afc[0] = *(const bf16x8*)pa;
    afc[1] = *(const bf16x8*)(pa + 16 * Eq);
#pragma unroll
    for (int j = 0; j < 4; ++j) bfc[j] = *(const bf16x8*)(pw + (size_t)j * 16 * Eq);

    for (int e0 = 0; e0 < Eq; e0 += 32) {
        bf16x8 afn[2], bfn[4];
        const int en = e0 + 32;
        if (en < Eq) {
            afn[0] = *(const bf16x8*)(pa + en);
            afn[1] = *(const bf16x8*)(pa + 16 * Eq + en);
#pragma unroll
            for (int j = 0; j < 4; ++j) bfn[j] = *(const bf16x8*)(pw + (size_t)j * 16 * Eq + en);
        }
#pragma unroll
        for (int i = 0; i < 2; ++i)
#pragma unroll
            for (int j = 0; j < 4; ++j)
                acc[i][j] = __builtin_amdgcn_mfma_f32_16x16x32_bf16(afc[i], bfc[j], acc[i][j], 0, 0, 0);
        if (en < Eq) {
            afc[0] = afn[0]; afc[1] = afn[1];
#pragma unroll
            for (int j = 0; j < 4; ++j) bfc[j] = bfn[j];
        }
    }

    const int h = n0 >> 6;
#pragma unroll
    for (int i = 0; i < 2; ++i) {
        float ss[4] = {0.f, 0.f, 0.f, 0.f};
#pragma unroll
        for (int r = 0; r < 4; ++r) {
            int tok = m0 + i * 16 + quad * 4 + r;
            int b = tok >> 11, l = tok & 2047;
#pragma unroll
            for (int j = 0; j < 4; ++j) {
                int feat = n0 + j * 16 + l15;
                int d = feat & 63;
                short sb = f2bf(acc[i][j][r]);
                float sv = bf2f(sb);
                ss[r] += sv * sv;
                size_t idx = transposed
                                 ? (((size_t)(b * Hq + h) * Dq + d) * Lq + l)
                                 : (((size_t)(b * Hq + h) * Lq + l) * Dq + d);
                outb[idx] = sb;
            }
        }
        if (x2 != nullptr) {
#pragma unroll
            for (int r = 0; r < 4; ++r) {
#pragma unroll
                for (int off = 1; off < 16; off <<= 1) ss[r] += __shfl_xor(ss[r], off);
            }
            if (l15 == 0) {
#pragma unroll
                for (int r = 0; r < 4; ++r) {
                    int tok = m0 + i * 16 + quad * 4 + r;
                    int b = tok >> 11, l = tok & 2047;
                    x2[(size_t)(b * Hq + h) * Lq + l] = ss[r];
                }
            }
        }
    }
}

// Pass A: flash partials, scores = -||q-k||, fixed softmax max = 0.
// Fully wave-private (no cross-wave LDS, no atomics): wave w handles
// q-tile (blockIdx.x*2 + (w&1)) and key half (w>>1). Writes raw O partial
// (bf16) and lsum partial (f32) to global.
// Grid (64, B*H) = 2048 blocks, 256 threads.
__global__ __launch_bounds__(256) void flash_part_kernel(const short* __restrict__ qb,
                                                         const short* __restrict__ kb,
                                                         const short* __restrict__ vT,
                                                         const float* __restrict__ q2,
                                                         const float* __restrict__ k2,
                                                         short* __restrict__ numpart,
                                                         float* __restrict__ denpart) {
    const int wave = threadIdx.x >> 6;
    const int lane = threadIdx.x & 63;
    const int l15 = lane & 15, quad = lane >> 4;
    const int bh = blockIdx.y;
    const int qt = blockIdx.x * 2 + (wave & 1);
    const int q0 = qt * 16;
    const int ks = wave >> 1;
    const short* qbh = qb + (size_t)bh * Lq * Dq;
    const short* kbh = kb + (size_t)bh * Lq * Dq;
    const short* vbh = vT + (size_t)bh * Dq * Lq;
    const float* q2h = q2 + (size_t)bh * Lq;
    const float* k2h = k2 + (size_t)bh * Lq;

    // wave-private P transpose buffer (round-3-proven pattern)
    __shared__ __align__(16) short plds[4][16 * 56];
    short* pl = plds[wave];

    const short* qp = qbh + (size_t)(q0 + l15) * Dq + quad * 8;
    bf16x8 qf0 = *(const bf16x8*)qp;
    bf16x8 qf1 = *(const bf16x8*)(qp + 32);
    float q2r[4];
#pragma unroll
    for (int r = 0; r < 4; ++r) q2r[r] = q2h[q0 + quad * 4 + r];

    f32x4 o[4] = {};
    float lsum[4] = {0.f, 0.f, 0.f, 0.f};
    const int kbase = ks * (Lq / 2);

    for (int kc = 0; kc < Lq / 2; kc += 32) {
        const int k0 = kbase + kc;
        const short* kp = kbh + (size_t)(k0 + l15) * Dq + quad * 8;
        bf16x8 kf00 = *(const bf16x8*)kp;
        bf16x8 kf01 = *(const bf16x8*)(kp + 32);
        bf16x8 kf10 = *(const bf16x8*)(kp + 16 * Dq);
        bf16x8 kf11 = *(const bf16x8*)(kp + 16 * Dq + 32);
        bf16x8 vf[4];
#pragma unroll
        for (int f = 0; f < 4; ++f)
            vf[f] = *(const bf16x8*)(vbh + (size_t)(f * 16 + l15) * Lq + k0 + quad * 8);
        float k2c0 = k2h[k0 + l15];
        float k2c1 = k2h[k0 + 16 + l15];

        f32x4 s0 = {0.f, 0.f, 0.f, 0.f}, s1 = {0.f, 0.f, 0.f, 0.f};
        s0 = __builtin_amdgcn_mfma_f32_16x16x32_bf16(qf0, kf00, s0, 0, 0, 0);
        s0 = __builtin_amdgcn_mfma_f32_16x16x32_bf16(qf1, kf01, s0, 0, 0, 0);
        s1 = __builtin_amdgcn_mfma_f32_16x16x32_bf16(qf0, kf10, s1, 0, 0, 0);
        s1 = __builtin_amdgcn_mfma_f32_16x16x32_bf16(qf1, kf11, s1, 0, 0, 0);

#pragma unroll
        for (int r = 0; r < 4; ++r) {
            float d0 = fmaxf(q2r[r] + k2c0 - 2.f * s0[r], 0.f);
            float d1 = fmaxf(q2r[r] + k2c1 - 2.f * s1[r], 0.f);
            float p0 = __expf(-__builtin_amdgcn_sqrtf(d0));
            float p1 = __expf(-__builtin_amdgcn_sqrtf(d1));
            lsum[r] += p0 + p1;
            pl[(quad * 4 + r) * 56 + l15] = f2bf(p0);
            pl[(quad * 4 + r) * 56 + 16 + l15] = f2bf(p1);
        }
        asm volatile("s_waitcnt lgkmcnt(0)" ::: "memory");
        bf16x8 pa = *(const bf16x8*)(pl + l15 * 56 + quad * 8);
#pragma unroll
        for (int f = 0; f < 4; ++f)
            o[f] = __builtin_amdgcn_mfma_f32_16x16x32_bf16(pa, vf[f], o[f], 0, 0, 0);
    }

    // reduce lsum over the 16 l15 lanes (cols); all lanes end up with the total
#pragma unroll
    for (int r = 0; r < 4; ++r) {
#pragma unroll
        for (int off = 1; off < 16; off <<= 1) lsum[r] += __shfl_xor(lsum[r], off);
    }

    // write wave-private partials to global: numpart[bh][qt][ks][row][d] (bf16),
    // denpart[bh][qt][ks][row] (f32)
    const size_t base = (((size_t)bh * 128 + qt) * 2 + ks) * 16;
    short* np_ = numpart + base * 64;
#pragma unroll
    for (int f = 0; f < 4; ++f)
#pragma unroll
        for (int r = 0; r < 4; ++r)
            np_[(quad * 4 + r) * 64 + f * 16 + l15] = f2bf(o[f][r]);
    if (l15 == 0) {
#pragma unroll
        for (int r = 0; r < 4; ++r) denpart[base + quad * 4 + r] = lsum[r];
    }
}

// Pass B: combine key-half partials, normalize per q-row, sum over q-rows.
// One block per bh; osum[bh][d] written directly (no atomics, no pre-zero).
__global__ __launch_bounds__(256) void combine_kernel(const short* __restrict__ numpart,
                                                      const float* __restrict__ denpart,
                                                      float* __restrict__ osum) {
    const int bh = blockIdx.x;
    const int d = threadIdx.x & 63;
    const int w2 = threadIdx.x >> 6;
    float acc = 0.f;
    for (int qt = w2; qt < 128; qt += 4) {
        const size_t b0 = ((size_t)bh * 128 + qt) * 32;  // ks=0 rows; ks=1 at +16
#pragma unroll
        for (int row = 0; row < 16; ++row) {
            float den = denpart[b0 + row] + denpart[b0 + 16 + row];
            float num = bf2f(numpart[(b0 + row) * 64 + d]) +
                        bf2f(numpart[(b0 + 16 + row) * 64 + d]);
            acc += num / den;
        }
    }
    __shared__ float red[256];
    red[threadIdx.x] = acc;
    __syncthreads();
    if (threadIdx.x < 64)
        osum[(size_t)bh * Dq + threadIdx.x] =
            red[threadIdx.x] + red[threadIdx.x + 64] +
            red[threadIdx.x + 128] + red[threadIdx.x + 192];
}

// out[b,j] = sum_e osum[b,e] * Wo[j,e]; one wave per output element
__global__ __launch_bounds__(256) void outproj_kernel(const float* __restrict__ osum,
                                                      const float* __restrict__ Wo,
                                                      float* __restrict__ out) {
    int idx = blockIdx.x * 4 + (threadIdx.x >> 6);
    int lane = threadIdx.x & 63;
    int b = idx >> 10, j = idx & 1023;
    const float* o = osum + (size_t)b * Eq;
    const float* w = Wo + (size_t)j * Eq;
    float4 s4 = {0.f, 0.f, 0.f, 0.f};
    for (int e = lane * 4; e < Eq; e += 256) {
        float4 ov = *(const float4*)(o + e);
        float4 wv = *(const float4*)(w + e);
        s4.x += ov.x * wv.x; s4.y += ov.y * wv.y;
        s4.z += ov.z * wv.z; s4.w += ov.w * wv.w;
    }
    float s = s4.x + s4.y + s4.z + s4.w;
#pragma unroll
    for (int off = 1; off < 64; off <<= 1) s += __shfl_xor(s, off);
    if (lane == 0) out[idx] = s;
}

extern "C" void kernel_launch(void* const* d_in, const int* in_sizes, int n_in,
                              void* d_out, int out_size, void* d_ws, size_t ws_size,
                              hipStream_t stream) {
    const float* Q  = (const float*)d_in[0];
    const float* K  = (const float*)d_in[1];
    const float* V  = (const float*)d_in[2];
    const float* Wq = (const float*)d_in[3];
    const float* Wk = (const float*)d_in[4];
    const float* Wv = (const float*)d_in[5];
    const float* Wo = (const float*)d_in[6];
    float* out = (float*)d_out;

    char* ws = (char*)d_ws;
    // [0,8M) qb | [8M,16M) kb | [16M,24M) vT | q2 | k2 | osum | [25M,55M) castb
    // numpart (16 MB) + denpart (512 KB) OVERLAY castb (dead after proj3).
    short* qb = (short*)ws;
    short* kb = (short*)(ws + (size_t)(8 << 20));
    short* vT = (short*)(ws + (size_t)(16 << 20));
    float* q2 = (float*)(ws + (size_t)(24 << 20));
    float* k2 = (float*)(ws + (size_t)(24 << 20) + (256 << 10));
    float* os = (float*)(ws + (size_t)(24 << 20) + (512 << 10));
    short* castb = (short*)(ws + (size_t)(25 << 20));
    short* numpart = (short*)(ws + (size_t)(25 << 20));           // 16 MB overlay
    float* denpart = (float*)(ws + (size_t)(41 << 20));           // 512 KB

    cast_all<<<15360, 256, 0, stream>>>(Q, K, V, Wq, Wk, Wv, castb);
    proj3_kernel<<<dim3(64, 24), 256, 0, stream>>>(castb, qb, kb, vT, q2, k2);
    flash_part_kernel<<<dim3(64, 32), 256, 0, stream>>>(qb, kb, vT, q2, k2, numpart, denpart);
    combine_kernel<<<32, 256, 0, stream>>>(numpart, denpart, os);
    outproj_kernel<<<512, 256, 0, stream>>>(os, Wo, out);
}

// Round 7
// 374.157 us; speedup vs baseline: 1.3466x; 1.3466x over previous
//
#include <hip/hip_runtime.h>
#include <math.h>

#define Bq 2
#define Lq 2048
#define Eq 1024
#define Hq 16
#define Dq 64

typedef __attribute__((ext_vector_type(8))) short bf16x8;
typedef __attribute__((ext_vector_type(4))) short bf16x4;
typedef __attribute__((ext_vector_type(4))) float f32x4;

__device__ __forceinline__ short f2bf(float f) {
    union { float f; unsigned u; } x; x.f = f;
    unsigned r = x.u + 0x7FFFu + ((x.u >> 16) & 1u);
    return (short)(r >> 16);
}
__device__ __forceinline__ float bf2f(short s) {
    union { unsigned u; float f; } x;
    x.u = ((unsigned)(unsigned short)s) << 16;
    return x.f;
}

// Cast Q,K,V (4096x1024 f32) and Wq,Wk,Wv (1024x1024 f32) to bf16, laid out
// consecutively in `out`: [Xq | Xk | Xv | Wqb | Wkb | Wvb]. Tail blocks zero `os`.
__global__ __launch_bounds__(256) void cast_all(const float* __restrict__ Q,
                                                const float* __restrict__ K,
                                                const float* __restrict__ V,
                                                const float* __restrict__ Wq,
                                                const float* __restrict__ Wk,
                                                const float* __restrict__ Wv,
                                                short* __restrict__ out,
                                                float* __restrict__ os) {
    const size_t NX = (size_t)4096 * 1024 / 4;  // float4 count per X
    const size_t NW = (size_t)1024 * 1024 / 4;  // float4 count per W
    const size_t TOT = 3 * NX + 3 * NW;
    size_t id = (size_t)blockIdx.x * 256 + threadIdx.x;
    if (id >= TOT) {
        size_t z = id - TOT;
        if (z < (size_t)(Bq * Eq / 4)) {
            float4 zv = {0.f, 0.f, 0.f, 0.f};
            ((float4*)os)[z] = zv;
        }
        return;
    }
    const float* src; size_t off;
    if (id < NX)              { src = Q;  off = id; }
    else if (id < 2 * NX)     { src = K;  off = id - NX; }
    else if (id < 3 * NX)     { src = V;  off = id - 2 * NX; }
    else if (id < 3 * NX + NW)     { src = Wq; off = id - 3 * NX; }
    else if (id < 3 * NX + 2 * NW) { src = Wk; off = id - 3 * NX - NW; }
    else                           { src = Wv; off = id - 3 * NX - 2 * NW; }
    float4 v = ((const float4*)src)[off];
    bf16x4 s;
    s[0] = f2bf(v.x); s[1] = f2bf(v.y); s[2] = f2bf(v.z); s[3] = f2bf(v.w);
    ((bf16x4*)out)[id] = s;
}

// All three projections in one kernel. blockIdx.y = pidx*8 + ntile.
// out[tok,feat] = sum_e Xb[tok,e]*Wb[feat,e]; bf16 in, fp32 accum, bf16 out.
// pidx 0/1 -> (B,H,L,D) + sumsq into q2/k2 ; pidx 2 -> (B,H,D,L), no sumsq.
// Block tile 64(M)x128(N), wave tile 32x64; register double-buffered K loop.
__global__ __launch_bounds__(256) void proj3_kernel(const short* __restrict__ castb,
                                                    short* __restrict__ qb,
                                                    short* __restrict__ kb,
                                                    short* __restrict__ vT,
                                                    float* __restrict__ q2,
                                                    float* __restrict__ k2) {
    const int wave = threadIdx.x >> 6;
    const int lane = threadIdx.x & 63;
    const int l15 = lane & 15, quad = lane >> 4;
    const int pidx = blockIdx.y >> 3;
    const short* Xb = castb + (size_t)pidx * 4096 * 1024;
    const short* Wb = castb + (size_t)3 * 4096 * 1024 + (size_t)pidx * 1024 * 1024;
    short* outb = (pidx == 0) ? qb : (pidx == 1) ? kb : vT;
    float* x2 = (pidx == 0) ? q2 : (pidx == 1) ? k2 : nullptr;
    const int transposed = (pidx == 2);
    const int m0 = blockIdx.x * 64 + (wave & 1) * 32;
    const int n0 = (blockIdx.y & 7) * 128 + (wave >> 1) * 64;

    const short* pa = Xb + (size_t)(m0 + l15) * Eq + quad * 8;
    const short* pw = Wb + (size_t)(n0 + l15) * Eq + quad * 8;

    f32x4 acc[2][4] = {};
    bf16x8 afc[2], bfc[4];
    afc[0] = *(const bf16x8*)pa;
    afc[1] = *(const bf16x8*)(pa + 16 * Eq);
#pragma unroll
    for (int j = 0; j < 4; ++j) bfc[j] = *(const bf16x8*)(pw + (size_t)j * 16 * Eq);

    for (int e0 = 0; e0 < Eq; e0 += 32) {
        bf16x8 afn[2], bfn[4];
        const int en = e0 + 32;
        if (en < Eq) {
            afn[0] = *(const bf16x8*)(pa + en);
            afn[1] = *(const bf16x8*)(pa + 16 * Eq + en);
#pragma unroll
            for (int j = 0; j < 4; ++j) bfn[j] = *(const bf16x8*)(pw + (size_t)j * 16 * Eq + en);
        }
#pragma unroll
        for (int i = 0; i < 2; ++i)
#pragma unroll
            for (int j = 0; j < 4; ++j)
                acc[i][j] = __builtin_amdgcn_mfma_f32_16x16x32_bf16(afc[i], bfc[j], acc[i][j], 0, 0, 0);
        if (en < Eq) {
            afc[0] = afn[0]; afc[1] = afn[1];
#pragma unroll
            for (int j = 0; j < 4; ++j) bfc[j] = bfn[j];
        }
    }

    const int h = n0 >> 6;
#pragma unroll
    for (int i = 0; i < 2; ++i) {
        float ss[4] = {0.f, 0.f, 0.f, 0.f};
#pragma unroll
        for (int r = 0; r < 4; ++r) {
            int tok = m0 + i * 16 + quad * 4 + r;
            int b = tok >> 11, l = tok & 2047;
#pragma unroll
            for (int j = 0; j < 4; ++j) {
                int feat = n0 + j * 16 + l15;
                int d = feat & 63;
                short sb = f2bf(acc[i][j][r]);
                float sv = bf2f(sb);
                ss[r] += sv * sv;
                size_t idx = transposed
                                 ? (((size_t)(b * Hq + h) * Dq + d) * Lq + l)
                                 : (((size_t)(b * Hq + h) * Lq + l) * Dq + d);
                outb[idx] = sb;
            }
        }
        if (x2 != nullptr) {
#pragma unroll
            for (int r = 0; r < 4; ++r) {
#pragma unroll
                for (int off = 1; off < 16; off <<= 1) ss[r] += __shfl_xor(ss[r], off);
            }
            if (l15 == 0) {
#pragma unroll
                for (int r = 0; r < 4; ++r) {
                    int tok = m0 + i * 16 + quad * 4 + r;
                    int b = tok >> 11, l = tok & 2047;
                    x2[(size_t)(b * Hq + h) * Lq + l] = ss[r];
                }
            }
        }
    }
}

// Pass A: flash partials, scores = -||q-k||, fixed softmax max = 0.
// Wave-private task: wave w of block (bx,bh) handles q-group qg = bx*2+(w&1)
// (32 q-rows) against key half ks = w>>1, in 64-key iterations with register
// prefetch of the next K tile. Writes raw O partials (bf16) + lsum (f32).
// Grid (32, B*H) = 1024 blocks, 256 threads.
__global__ __launch_bounds__(256) void flash_part_kernel(const short* __restrict__ qb,
                                                         const short* __restrict__ kb,
                                                         const short* __restrict__ vT,
                                                         const float* __restrict__ q2,
                                                         const float* __restrict__ k2,
                                                         short* __restrict__ numpart,
                                                         float* __restrict__ denpart) {
    const int wave = threadIdx.x >> 6;
    const int lane = threadIdx.x & 63;
    const int l15 = lane & 15, quad = lane >> 4;
    const int bh = blockIdx.y;
    const int qg = blockIdx.x * 2 + (wave & 1);   // 32-row q group
    const int q0 = qg * 32;
    const int ks = wave >> 1;                     // key half
    const short* qbh = qb + (size_t)bh * Lq * Dq;
    const short* kbh = kb + (size_t)bh * Lq * Dq;
    const short* vbh = vT + (size_t)bh * Dq * Lq;
    const float* q2h = q2 + (size_t)bh * Lq;
    const float* k2h = k2 + (size_t)bh * Lq;

    // wave-private P transpose buffers: per qtile 16 rows x 64 key-cols,
    // row stride 72 shorts (144 B) for bank spread.
    __shared__ __align__(16) short plds[4][2][16 * 72];

    bf16x8 qf[2][2];
    float q2r[2][4];
#pragma unroll
    for (int t = 0; t < 2; ++t) {
        const short* qp = qbh + (size_t)(q0 + t * 16 + l15) * Dq + quad * 8;
        qf[t][0] = *(const bf16x8*)qp;
        qf[t][1] = *(const bf16x8*)(qp + 32);
#pragma unroll
        for (int r = 0; r < 4; ++r) q2r[t][r] = q2h[q0 + t * 16 + quad * 4 + r];
    }

    f32x4 o[2][4] = {};
    float lsum[2][4] = {};
    const int kbase = ks * (Lq / 2);

    // preload first K tile (4 x 16 keys)
    bf16x8 kfc[4][2];
    float k2c[4];
    {
        const short* kp = kbh + (size_t)(kbase + l15) * Dq + quad * 8;
#pragma unroll
        for (int kt = 0; kt < 4; ++kt) {
            kfc[kt][0] = *(const bf16x8*)(kp + (size_t)kt * 16 * Dq);
            kfc[kt][1] = *(const bf16x8*)(kp + (size_t)kt * 16 * Dq + 32);
            k2c[kt] = k2h[kbase + kt * 16 + l15];
        }
    }

#pragma unroll 1
    for (int kc = 0; kc < Lq / 2; kc += 64) {
        const int k0 = kbase + kc;
        // V loads for this iteration (consumed late -> latency hidden by VALU phase)
        bf16x8 vf[2][4];
#pragma unroll
        for (int kc2 = 0; kc2 < 2; ++kc2)
#pragma unroll
            for (int f = 0; f < 4; ++f)
                vf[kc2][f] = *(const bf16x8*)(vbh + (size_t)(f * 16 + l15) * Lq +
                                              k0 + kc2 * 32 + quad * 8);
        // prefetch next K tile
        bf16x8 kfn[4][2];
        float k2n[4];
        const bool has_next = (kc + 64) < (Lq / 2);
        if (has_next) {
            const short* kp = kbh + (size_t)(k0 + 64 + l15) * Dq + quad * 8;
#pragma unroll
            for (int kt = 0; kt < 4; ++kt) {
                kfn[kt][0] = *(const bf16x8*)(kp + (size_t)kt * 16 * Dq);
                kfn[kt][1] = *(const bf16x8*)(kp + (size_t)kt * 16 * Dq + 32);
                k2n[kt] = k2h[k0 + 64 + kt * 16 + l15];
            }
        }

        // S = q.k^T for 2 qtiles x 4 ktiles (K resident in registers -> no wait)
        f32x4 s[2][4];
#pragma unroll
        for (int t = 0; t < 2; ++t)
#pragma unroll
            for (int kt = 0; kt < 4; ++kt) {
                f32x4 z = {0.f, 0.f, 0.f, 0.f};
                z = __builtin_amdgcn_mfma_f32_16x16x32_bf16(qf[t][0], kfc[kt][0], z, 0, 0, 0);
                z = __builtin_amdgcn_mfma_f32_16x16x32_bf16(qf[t][1], kfc[kt][1], z, 0, 0, 0);
                s[t][kt] = z;
            }

        // scores -> p = exp(-sqrt(d2)), accumulate lsum, write P^T tiles to LDS
#pragma unroll
        for (int t = 0; t < 2; ++t) {
            short* pl = plds[wave][t];
#pragma unroll
            for (int kt = 0; kt < 4; ++kt)
#pragma unroll
                for (int r = 0; r < 4; ++r) {
                    float d2 = fmaxf(q2r[t][r] + k2c[kt] - 2.f * s[t][kt][r], 0.f);
                    float pv = __expf(-__builtin_amdgcn_sqrtf(d2));
                    lsum[t][r] += pv;
                    pl[(quad * 4 + r) * 72 + kt * 16 + l15] = f2bf(pv);
                }
        }
        // P (A-layout) from LDS, PV MFMAs (compiler inserts the lgkm waits)
#pragma unroll
        for (int t = 0; t < 2; ++t) {
            const short* pl = plds[wave][t];
#pragma unroll
            for (int kc2 = 0; kc2 < 2; ++kc2) {
                bf16x8 pa = *(const bf16x8*)(pl + l15 * 72 + kc2 * 32 + quad * 8);
#pragma unroll
                for (int f = 0; f < 4; ++f)
                    o[t][f] = __builtin_amdgcn_mfma_f32_16x16x32_bf16(pa, vf[kc2][f], o[t][f], 0, 0, 0);
            }
        }
        if (has_next) {
#pragma unroll
            for (int kt = 0; kt < 4; ++kt) {
                kfc[kt][0] = kfn[kt][0];
                kfc[kt][1] = kfn[kt][1];
                k2c[kt] = k2n[kt];
            }
        }
    }

    // reduce lsum over the 16 l15 lanes; write partials
#pragma unroll
    for (int t = 0; t < 2; ++t) {
#pragma unroll
        for (int r = 0; r < 4; ++r) {
#pragma unroll
            for (int off = 1; off < 16; off <<= 1) lsum[t][r] += __shfl_xor(lsum[t][r], off);
        }
        const int qt = qg * 2 + t;
        const size_t base = (((size_t)bh * 128 + qt) * 2 + ks) * 16;
        short* np_ = numpart + base * 64;
#pragma unroll
        for (int f = 0; f < 4; ++f)
#pragma unroll
            for (int r = 0; r < 4; ++r)
                np_[(quad * 4 + r) * 64 + f * 16 + l15] = f2bf(o[t][f][r]);
        if (l15 == 0) {
#pragma unroll
            for (int r = 0; r < 4; ++r) denpart[base + quad * 4 + r] = lsum[t][r];
        }
    }
}

// Pass B: combine key-half partials, normalize per q-row, sum over q-rows.
// Grid 128: block = (bh, quarter of qtiles); atomicAdd into pre-zeroed osum.
__global__ __launch_bounds__(256) void combine_kernel(const short* __restrict__ numpart,
                                                      const float* __restrict__ denpart,
                                                      float* __restrict__ osum) {
    const int bh = blockIdx.x >> 2;
    const int qs = blockIdx.x & 3;
    const int d = threadIdx.x & 63;
    const int w2 = threadIdx.x >> 6;
    float acc = 0.f;
    for (int qt = qs * 32 + w2; qt < qs * 32 + 32; qt += 4) {
        const size_t b0 = ((size_t)bh * 128 + qt) * 32;  // ks=0 rows; ks=1 at +16
#pragma unroll
        for (int row = 0; row < 16; ++row) {
            float den = denpart[b0 + row] + denpart[b0 + 16 + row];
            float num = bf2f(numpart[(b0 + row) * 64 + d]) +
                        bf2f(numpart[(b0 + 16 + row) * 64 + d]);
            acc += num / den;
        }
    }
    __shared__ float red[256];
    red[threadIdx.x] = acc;
    __syncthreads();
    if (threadIdx.x < 64)
        atomicAdd(&osum[(size_t)bh * Dq + threadIdx.x],
                  red[threadIdx.x] + red[threadIdx.x + 64] +
                  red[threadIdx.x + 128] + red[threadIdx.x + 192]);
}

// out[b,j] = sum_e osum[b,e] * Wo[j,e]; one wave per output element
__global__ __launch_bounds__(256) void outproj_kernel(const float* __restrict__ osum,
                                                      const float* __restrict__ Wo,
                                                      float* __restrict__ out) {
    int idx = blockIdx.x * 4 + (threadIdx.x >> 6);
    int lane = threadIdx.x & 63;
    int b = idx >> 10, j = idx & 1023;
    const float* o = osum + (size_t)b * Eq;
    const float* w = Wo + (size_t)j * Eq;
    float4 s4 = {0.f, 0.f, 0.f, 0.f};
    for (int e = lane * 4; e < Eq; e += 256) {
        float4 ov = *(const float4*)(o + e);
        float4 wv = *(const float4*)(w + e);
        s4.x += ov.x * wv.x; s4.y += ov.y * wv.y;
        s4.z += ov.z * wv.z; s4.w += ov.w * wv.w;
    }
    float s = s4.x + s4.y + s4.z + s4.w;
#pragma unroll
    for (int off = 1; off < 64; off <<= 1) s += __shfl_xor(s, off);
    if (lane == 0) out[idx] = s;
}

extern "C" void kernel_launch(void* const* d_in, const int* in_sizes, int n_in,
                              void* d_out, int out_size, void* d_ws, size_t ws_size,
                              hipStream_t stream) {
    const float* Q  = (const float*)d_in[0];
    const float* K  = (const float*)d_in[1];
    const float* V  = (const float*)d_in[2];
    const float* Wq = (const float*)d_in[3];
    const float* Wk = (const float*)d_in[4];
    const float* Wv = (const float*)d_in[5];
    const float* Wo = (const float*)d_in[6];
    float* out = (float*)d_out;

    char* ws = (char*)d_ws;
    // [0,8M) qb | [8M,16M) kb | [16M,24M) vT | q2 | k2 | osum | [25M,55M) castb
    // numpart (16 MB) + denpart (512 KB) OVERLAY castb (dead after proj3).
    short* qb = (short*)ws;
    short* kb = (short*)(ws + (size_t)(8 << 20));
    short* vT = (short*)(ws + (size_t)(16 << 20));
    float* q2 = (float*)(ws + (size_t)(24 << 20));
    float* k2 = (float*)(ws + (size_t)(24 << 20) + (256 << 10));
    float* os = (float*)(ws + (size_t)(24 << 20) + (512 << 10));
    short* castb = (short*)(ws + (size_t)(25 << 20));
    short* numpart = (short*)(ws + (size_t)(25 << 20));           // 16 MB overlay
    float* denpart = (float*)(ws + (size_t)(41 << 20));           // 512 KB

    cast_all<<<15362, 256, 0, stream>>>(Q, K, V, Wq, Wk, Wv, castb, os);
    proj3_kernel<<<dim3(64, 24), 256, 0, stream>>>(castb, qb, kb, vT, q2, k2);
    flash_part_kernel<<<dim3(32, 32), 256, 0, stream>>>(qb, kb, vT, q2, k2, numpart, denpart);
    combine_kernel<<<128, 256, 0, stream>>>(numpart, denpart, os);
    outproj_kernel<<<512, 256, 0, stream>>>(os, Wo, out);
}

// Round 8
// 294.667 us; speedup vs baseline: 1.7098x; 1.2698x over previous
//
#include <hip/hip_runtime.h>
#include <math.h>

#define Bq 2
#define Lq 2048
#define Eq 1024
#define Hq 16
#define Dq 64

typedef __attribute__((ext_vector_type(8))) short bf16x8;
typedef __attribute__((ext_vector_type(4))) short bf16x4;
typedef __attribute__((ext_vector_type(4))) float f32x4;

typedef __attribute__((address_space(1))) const void gconst_void;
typedef __attribute__((address_space(3))) void lds_void;
#define GLOAD_LDS16(g, l) \
    __builtin_amdgcn_global_load_lds((gconst_void*)(g), (lds_void*)(l), 16, 0, 0)

__device__ __forceinline__ short f2bf(float f) {
    union { float f; unsigned u; } x; x.f = f;
    unsigned r = x.u + 0x7FFFu + ((x.u >> 16) & 1u);
    return (short)(r >> 16);
}
__device__ __forceinline__ float bf2f(short s) {
    union { unsigned u; float f; } x;
    x.u = ((unsigned)(unsigned short)s) << 16;
    return x.f;
}

// Cast Q,K,V (4096x1024 f32) and Wq,Wk,Wv (1024x1024 f32) to bf16, laid out
// consecutively in `out`: [Xq | Xk | Xv | Wqb | Wkb | Wvb]. Tail blocks zero `os`.
__global__ __launch_bounds__(256) void cast_all(const float* __restrict__ Q,
                                                const float* __restrict__ K,
                                                const float* __restrict__ V,
                                                const float* __restrict__ Wq,
                                                const float* __restrict__ Wk,
                                                const float* __restrict__ Wv,
                                                short* __restrict__ out,
                                                float* __restrict__ os) {
    const size_t NX = (size_t)4096 * 1024 / 4;  // float4 count per X
    const size_t NW = (size_t)1024 * 1024 / 4;  // float4 count per W
    const size_t TOT = 3 * NX + 3 * NW;
    size_t id = (size_t)blockIdx.x * 256 + threadIdx.x;
    if (id >= TOT) {
        size_t z = id - TOT;
        if (z < (size_t)(Bq * Eq / 4)) {
            float4 zv = {0.f, 0.f, 0.f, 0.f};
            ((float4*)os)[z] = zv;
        }
        return;
    }
    const float* src; size_t off;
    if (id < NX)              { src = Q;  off = id; }
    else if (id < 2 * NX)     { src = K;  off = id - NX; }
    else if (id < 3 * NX)     { src = V;  off = id - 2 * NX; }
    else if (id < 3 * NX + NW)     { src = Wq; off = id - 3 * NX; }
    else if (id < 3 * NX + 2 * NW) { src = Wk; off = id - 3 * NX - NW; }
    else                           { src = Wv; off = id - 3 * NX - 2 * NW; }
    float4 v = ((const float4*)src)[off];
    bf16x4 s;
    s[0] = f2bf(v.x); s[1] = f2bf(v.y); s[2] = f2bf(v.z); s[3] = f2bf(v.w);
    ((bf16x4*)out)[id] = s;
}

// All three projections, m97-style LDS-staged GEMM.
// blockIdx.y = pidx*8 + ntile. Block tile 128(M)x128(N), BK=32, wave tile 64x64.
// Staging: global_load_lds width=16 (coalesced 4-lanes-per-row), 2-barrier K loop,
// ds_read_b128 fragment reads. Epilogue: bf16 scatter to (B,H,L,D) / (B,H,D,L)
// + fused sum-of-squares for q/k.
__global__ __launch_bounds__(256) void proj3_kernel(const short* __restrict__ castb,
                                                    short* __restrict__ qb,
                                                    short* __restrict__ kb,
                                                    short* __restrict__ vT,
                                                    float* __restrict__ q2,
                                                    float* __restrict__ k2) {
    const int wave = threadIdx.x >> 6;
    const int lane = threadIdx.x & 63;
    const int l15 = lane & 15, quad = lane >> 4;
    const int pidx = blockIdx.y >> 3;
    const short* Xb = castb + (size_t)pidx * 4096 * 1024;
    const short* Wb = castb + (size_t)3 * 4096 * 1024 + (size_t)pidx * 1024 * 1024;
    short* outb = (pidx == 0) ? qb : (pidx == 1) ? kb : vT;
    float* x2 = (pidx == 0) ? q2 : (pidx == 1) ? k2 : nullptr;
    const int transposed = (pidx == 2);
    const int m0 = blockIdx.x * 128;
    const int n0 = (blockIdx.y & 7) * 128;
    const int wm = wave & 1, wn = wave >> 1;

    __shared__ __align__(16) short lds_a[128 * 32];
    __shared__ __align__(16) short lds_b[128 * 32];

    // staging: lane covers row (lane>>2), col (lane&3)*8 of a 16-row slab; each
    // wave stages rows [wave*16, wave*16+16) and [64+wave*16, ...).
    const int srow = lane >> 2;
    const int scol = (lane & 3) * 8;
    const short* gA = Xb + (size_t)(m0 + wave * 16 + srow) * Eq + scol;
    const short* gB = Wb + (size_t)(n0 + wave * 16 + srow) * Eq + scol;
    short* la0 = lds_a + wave * 16 * 32;   // wave-uniform LDS bases
    short* lb0 = lds_b + wave * 16 * 32;

    f32x4 acc[4][4] = {};

    for (int e0 = 0; e0 < Eq; e0 += 32) {
        __syncthreads();  // all waves done reading previous tile
        GLOAD_LDS16(gA + e0, la0);
        GLOAD_LDS16(gA + (size_t)64 * Eq + e0, la0 + 64 * 32);
        GLOAD_LDS16(gB + e0, lb0);
        GLOAD_LDS16(gB + (size_t)64 * Eq + e0, lb0 + 64 * 32);
        __syncthreads();  // staging drained (vmcnt(0) before barrier)

        bf16x8 af[4], bfr[4];
#pragma unroll
        for (int i = 0; i < 4; ++i)
            af[i] = *(const bf16x8*)(lds_a + (wm * 64 + i * 16 + l15) * 32 + quad * 8);
#pragma unroll
        for (int j = 0; j < 4; ++j)
            bfr[j] = *(const bf16x8*)(lds_b + (wn * 64 + j * 16 + l15) * 32 + quad * 8);
#pragma unroll
        for (int i = 0; i < 4; ++i)
#pragma unroll
            for (int j = 0; j < 4; ++j)
                acc[i][j] = __builtin_amdgcn_mfma_f32_16x16x32_bf16(af[i], bfr[j], acc[i][j], 0, 0, 0);
    }

    const int mw = m0 + wm * 64;
    const int nw = n0 + wn * 64;
    const int h = nw >> 6;  // wave's 64-col range is exactly one head
#pragma unroll
    for (int i = 0; i < 4; ++i) {
        float ss[4] = {0.f, 0.f, 0.f, 0.f};
#pragma unroll
        for (int r = 0; r < 4; ++r) {
            int tok = mw + i * 16 + quad * 4 + r;
            int b = tok >> 11, l = tok & 2047;
#pragma unroll
            for (int j = 0; j < 4; ++j) {
                int d = (nw + j * 16 + l15) & 63;
                short sb = f2bf(acc[i][j][r]);
                float sv = bf2f(sb);
                ss[r] += sv * sv;
                size_t idx = transposed
                                 ? (((size_t)(b * Hq + h) * Dq + d) * Lq + l)
                                 : (((size_t)(b * Hq + h) * Lq + l) * Dq + d);
                outb[idx] = sb;
            }
        }
        if (x2 != nullptr) {
#pragma unroll
            for (int r = 0; r < 4; ++r) {
#pragma unroll
                for (int off = 1; off < 16; off <<= 1) ss[r] += __shfl_xor(ss[r], off);
            }
            if (l15 == 0) {
#pragma unroll
                for (int r = 0; r < 4; ++r) {
                    int tok = mw + i * 16 + quad * 4 + r;
                    int b = tok >> 11, l = tok & 2047;
                    x2[(size_t)(b * Hq + h) * Lq + l] = ss[r];
                }
            }
        }
    }
}

// Pass A: flash partials, scores = -||q-k||, fixed softmax max = 0.
// Wave-private task: wave w of block (bx,bh) handles q-group qg = bx*2+(w&1)
// (32 q-rows) against key half ks = w>>1, in 64-key iterations with register
// prefetch of the next K tile. Writes raw O partials (bf16) + lsum (f32).
// Grid (32, B*H) = 1024 blocks, 256 threads.
__global__ __launch_bounds__(256) void flash_part_kernel(const short* __restrict__ qb,
                                                         const short* __restrict__ kb,
                                                         const short* __restrict__ vT,
                                                         const float* __restrict__ q2,
                                                         const float* __restrict__ k2,
                                                         short* __restrict__ numpart,
                                                         float* __restrict__ denpart) {
    const int wave = threadIdx.x >> 6;
    const int lane = threadIdx.x & 63;
    const int l15 = lane & 15, quad = lane >> 4;
    const int bh = blockIdx.y;
    const int qg = blockIdx.x * 2 + (wave & 1);   // 32-row q group
    const int q0 = qg * 32;
    const int ks = wave >> 1;                     // key half
    const short* qbh = qb + (size_t)bh * Lq * Dq;
    const short* kbh = kb + (size_t)bh * Lq * Dq;
    const short* vbh = vT + (size_t)bh * Dq * Lq;
    const float* q2h = q2 + (size_t)bh * Lq;
    const float* k2h = k2 + (size_t)bh * Lq;

    // wave-private P transpose buffers: per qtile 16 rows x 64 key-cols,
    // row stride 72 shorts (144 B) for bank spread.
    __shared__ __align__(16) short plds[4][2][16 * 72];

    bf16x8 qf[2][2];
    float q2r[2][4];
#pragma unroll
    for (int t = 0; t < 2; ++t) {
        const short* qp = qbh + (size_t)(q0 + t * 16 + l15) * Dq + quad * 8;
        qf[t][0] = *(const bf16x8*)qp;
        qf[t][1] = *(const bf16x8*)(qp + 32);
#pragma unroll
        for (int r = 0; r < 4; ++r) q2r[t][r] = q2h[q0 + t * 16 + quad * 4 + r];
    }

    f32x4 o[2][4] = {};
    float lsum[2][4] = {};
    const int kbase = ks * (Lq / 2);

    // preload first K tile (4 x 16 keys)
    bf16x8 kfc[4][2];
    float k2c[4];
    {
        const short* kp = kbh + (size_t)(kbase + l15) * Dq + quad * 8;
#pragma unroll
        for (int kt = 0; kt < 4; ++kt) {
            kfc[kt][0] = *(const bf16x8*)(kp + (size_t)kt * 16 * Dq);
            kfc[kt][1] = *(const bf16x8*)(kp + (size_t)kt * 16 * Dq + 32);
            k2c[kt] = k2h[kbase + kt * 16 + l15];
        }
    }

#pragma unroll 1
    for (int kc = 0; kc < Lq / 2; kc += 64) {
        const int k0 = kbase + kc;
        // V loads for this iteration (consumed late -> latency hidden by VALU phase)
        bf16x8 vf[2][4];
#pragma unroll
        for (int kc2 = 0; kc2 < 2; ++kc2)
#pragma unroll
            for (int f = 0; f < 4; ++f)
                vf[kc2][f] = *(const bf16x8*)(vbh + (size_t)(f * 16 + l15) * Lq +
                                              k0 + kc2 * 32 + quad * 8);
        // prefetch next K tile
        bf16x8 kfn[4][2];
        float k2n[4];
        const bool has_next = (kc + 64) < (Lq / 2);
        if (has_next) {
            const short* kp = kbh + (size_t)(k0 + 64 + l15) * Dq + quad * 8;
#pragma unroll
            for (int kt = 0; kt < 4; ++kt) {
                kfn[kt][0] = *(const bf16x8*)(kp + (size_t)kt * 16 * Dq);
                kfn[kt][1] = *(const bf16x8*)(kp + (size_t)kt * 16 * Dq + 32);
                k2n[kt] = k2h[k0 + 64 + kt * 16 + l15];
            }
        }

        // S = q.k^T for 2 qtiles x 4 ktiles (K resident in registers -> no wait)
        f32x4 s[2][4];
#pragma unroll
        for (int t = 0; t < 2; ++t)
#pragma unroll
            for (int kt = 0; kt < 4; ++kt) {
                f32x4 z = {0.f, 0.f, 0.f, 0.f};
                z = __builtin_amdgcn_mfma_f32_16x16x32_bf16(qf[t][0], kfc[kt][0], z, 0, 0, 0);
                z = __builtin_amdgcn_mfma_f32_16x16x32_bf16(qf[t][1], kfc[kt][1], z, 0, 0, 0);
                s[t][kt] = z;
            }

        // scores -> p = exp(-sqrt(d2)), accumulate lsum, write P^T tiles to LDS
#pragma unroll
        for (int t = 0; t < 2; ++t) {
            short* pl = plds[wave][t];
#pragma unroll
            for (int kt = 0; kt < 4; ++kt)
#pragma unroll
                for (int r = 0; r < 4; ++r) {
                    float d2 = fmaxf(q2r[t][r] + k2c[kt] - 2.f * s[t][kt][r], 0.f);
                    float pv = __expf(-__builtin_amdgcn_sqrtf(d2));
                    lsum[t][r] += pv;
                    pl[(quad * 4 + r) * 72 + kt * 16 + l15] = f2bf(pv);
                }
        }
        // P (A-layout) from LDS, PV MFMAs (compiler inserts the lgkm waits)
#pragma unroll
        for (int t = 0; t < 2; ++t) {
            const short* pl = plds[wave][t];
#pragma unroll
            for (int kc2 = 0; kc2 < 2; ++kc2) {
                bf16x8 pa = *(const bf16x8*)(pl + l15 * 72 + kc2 * 32 + quad * 8);
#pragma unroll
                for (int f = 0; f < 4; ++f)
                    o[t][f] = __builtin_amdgcn_mfma_f32_16x16x32_bf16(pa, vf[kc2][f], o[t][f], 0, 0, 0);
            }
        }
        if (has_next) {
#pragma unroll
            for (int kt = 0; kt < 4; ++kt) {
                kfc[kt][0] = kfn[kt][0];
                kfc[kt][1] = kfn[kt][1];
                k2c[kt] = k2n[kt];
            }
        }
    }

    // reduce lsum over the 16 l15 lanes; write partials
#pragma unroll
    for (int t = 0; t < 2; ++t) {
#pragma unroll
        for (int r = 0; r < 4; ++r) {
#pragma unroll
            for (int off = 1; off < 16; off <<= 1) lsum[t][r] += __shfl_xor(lsum[t][r], off);
        }
        const int qt = qg * 2 + t;
        const size_t base = (((size_t)bh * 128 + qt) * 2 + ks) * 16;
        short* np_ = numpart + base * 64;
#pragma unroll
        for (int f = 0; f < 4; ++f)
#pragma unroll
            for (int r = 0; r < 4; ++r)
                np_[(quad * 4 + r) * 64 + f * 16 + l15] = f2bf(o[t][f][r]);
        if (l15 == 0) {
#pragma unroll
            for (int r = 0; r < 4; ++r) denpart[base + quad * 4 + r] = lsum[t][r];
        }
    }
}

// Pass B: combine key-half partials, normalize per q-row, sum over q-rows.
// Grid 128: block = (bh, quarter of qtiles); atomicAdd into pre-zeroed osum.
__global__ __launch_bounds__(256) void combine_kernel(const short* __restrict__ numpart,
                                                      const float* __restrict__ denpart,
                                                      float* __restrict__ osum) {
    const int bh = blockIdx.x >> 2;
    const int qs = blockIdx.x & 3;
    const int d = threadIdx.x & 63;
    const int w2 = threadIdx.x >> 6;
    float acc = 0.f;
    for (int qt = qs * 32 + w2; qt < qs * 32 + 32; qt += 4) {
        const size_t b0 = ((size_t)bh * 128 + qt) * 32;  // ks=0 rows; ks=1 at +16
#pragma unroll
        for (int row = 0; row < 16; ++row) {
            float den = denpart[b0 + row] + denpart[b0 + 16 + row];
            float num = bf2f(numpart[(b0 + row) * 64 + d]) +
                        bf2f(numpart[(b0 + 16 + row) * 64 + d]);
            acc += num / den;
        }
    }
    __shared__ float red[256];
    red[threadIdx.x] = acc;
    __syncthreads();
    if (threadIdx.x < 64)
        atomicAdd(&osum[(size_t)bh * Dq + threadIdx.x],
                  red[threadIdx.x] + red[threadIdx.x + 64] +
                  red[threadIdx.x + 128] + red[threadIdx.x + 192]);
}

// out[b,j] = sum_e osum[b,e] * Wo[j,e]; one wave per output element
__global__ __launch_bounds__(256) void outproj_kernel(const float* __restrict__ osum,
                                                      const float* __restrict__ Wo,
                                                      float* __restrict__ out) {
    int idx = blockIdx.x * 4 + (threadIdx.x >> 6);
    int lane = threadIdx.x & 63;
    int b = idx >> 10, j = idx & 1023;
    const float* o = osum + (size_t)b * Eq;
    const float* w = Wo + (size_t)j * Eq;
    float4 s4 = {0.f, 0.f, 0.f, 0.f};
    for (int e = lane * 4; e < Eq; e += 256) {
        float4 ov = *(const float4*)(o + e);
        float4 wv = *(const float4*)(w + e);
        s4.x += ov.x * wv.x; s4.y += ov.y * wv.y;
        s4.z += ov.z * wv.z; s4.w += ov.w * wv.w;
    }
    float s = s4.x + s4.y + s4.z + s4.w;
#pragma unroll
    for (int off = 1; off < 64; off <<= 1) s += __shfl_xor(s, off);
    if (lane == 0) out[idx] = s;
}

extern "C" void kernel_launch(void* const* d_in, const int* in_sizes, int n_in,
                              void* d_out, int out_size, void* d_ws, size_t ws_size,
                              hipStream_t stream) {
    const float* Q  = (const float*)d_in[0];
    const float* K  = (const float*)d_in[1];
    const float* V  = (const float*)d_in[2];
    const float* Wq = (const float*)d_in[3];
    const float* Wk = (const float*)d_in[4];
    const float* Wv = (const float*)d_in[5];
    const float* Wo = (const float*)d_in[6];
    float* out = (float*)d_out;

    char* ws = (char*)d_ws;
    // [0,8M) qb | [8M,16M) kb | [16M,24M) vT | q2 | k2 | osum | [25M,55M) castb
    // numpart (16 MB) + denpart (512 KB) OVERLAY castb (dead after proj3).
    short* qb = (short*)ws;
    short* kb = (short*)(ws + (size_t)(8 << 20));
    short* vT = (short*)(ws + (size_t)(16 << 20));
    float* q2 = (float*)(ws + (size_t)(24 << 20));
    float* k2 = (float*)(ws + (size_t)(24 << 20) + (256 << 10));
    float* os = (float*)(ws + (size_t)(24 << 20) + (512 << 10));
    short* castb = (short*)(ws + (size_t)(25 << 20));
    short* numpart = (short*)(ws + (size_t)(25 << 20));           // 16 MB overlay
    float* denpart = (float*)(ws + (size_t)(41 << 20));           // 512 KB

    cast_all<<<15362, 256, 0, stream>>>(Q, K, V, Wq, Wk, Wv, castb, os);
    proj3_kernel<<<dim3(32, 24), 256, 0, stream>>>(castb, qb, kb, vT, q2, k2);
    flash_part_kernel<<<dim3(32, 32), 256, 0, stream>>>(qb, kb, vT, q2, k2, numpart, denpart);
    combine_kernel<<<128, 256, 0, stream>>>(numpart, denpart, os);
    outproj_kernel<<<512, 256, 0, stream>>>(os, Wo, out);
}